// Round 1
// baseline (333.433 us; speedup 1.0000x reference)
//
#include <hip/hip_runtime.h>
#include <hip/hip_bf16.h>
#include <math.h>

#define Hd 128
#define G3 384
#define Dd 128
#define Tt 256
#define Bb 1024
#define BB 4
#define CHUNK 16
#define NCH (Tt / CHUNK)

typedef __attribute__((ext_vector_type(8))) short short8;
typedef __attribute__((ext_vector_type(4))) float f32x4;

__device__ __forceinline__ short f2bf(float f) {
    unsigned u = __float_as_uint(f);
    u += 0x7fffu + ((u >> 16) & 1u);   // RNE
    return (short)(u >> 16);
}
__device__ __forceinline__ float bf2f(short s) {
    return __uint_as_float(((unsigned)(unsigned short)s) << 16);
}

// Pre-convert weights to bf16 in MFMA B-fragment-major layout.
// B-frag for 16x16x32: lane l holds B[kf*32 + 8*(l>>4) + j][nt*16 + (l&15)],
// with B[k][n] = W[n][k]  (we need W^T as the B operand) ->
// 8 consecutive f32 from row (nt*16 + (l&15)) of W.
__global__ void prep_weights(const float* __restrict__ Wih,
                             const float* __restrict__ Whh,
                             const float* __restrict__ fcW,
                             short* __restrict__ oIh, short* __restrict__ oHh,
                             short* __restrict__ oFc) {
    int t = blockIdx.x * 256 + threadIdx.x;
    if (t >= 14336) return;           // 24*4*64 + 24*4*64 + 8*4*64
    const float* src;
    short* dst;
    if (t < 6144)       { src = Wih; dst = oIh + t * 8; }
    else if (t < 12288) { t -= 6144;  src = Whh; dst = oHh + t * 8; }
    else                { t -= 12288; src = fcW; dst = oFc + t * 8; }
    int lane = t & 63, kf = (t >> 6) & 3, nt = t >> 8;
    const float* s = src + (nt * 16 + (lane & 15)) * 128 + kf * 32 + 8 * (lane >> 4);
#pragma unroll
    for (int j = 0; j < 8; j++) dst[j] = f2bf(s[j]);
}

// Fused GRU(+resets)+FC+ELU. grid=256 blocks (BB=4 batches each), 512 threads.
// Wave w owns gate-column tiles {w, w+8, w+16} (cols w*16..w*16+15 of r,z,n).
__global__ __launch_bounds__(512)
void gru_fused(const float* __restrict__ x, const float* __restrict__ h0,
               const int* __restrict__ done,
               const float* __restrict__ bih, const float* __restrict__ bhh,
               const float* __restrict__ fcb,
               const short* __restrict__ wIh, const short* __restrict__ wHh,
               const short* __restrict__ wFc,
               float* __restrict__ out, float* __restrict__ hlast) {
    __shared__ short xiL[64 * 384];   // xi chunk, bf16, XOR-swizzled (48 KB)
    __shared__ float ghL[4 * 384];    // gh for current step, f32
    __shared__ float hF[4 * 128];     // reset-applied h, f32
    __shared__ short hA[16 * 128];    // h as bf16 A-frags, swizzled, rows 4-15 zero
    __shared__ short fcA[64 * 128];   // h chunk for FC, bf16, swizzled (16 KB)
    __shared__ int doneL[64];

    const int tid = threadIdx.x;
    const int wv = tid >> 6, ln = tid & 63;
    const int l15 = ln & 15, lg = ln >> 4;
    const int bg0 = blockIdx.x * BB;

    // W_hh register-resident B-frags: 3 n-tiles x 4 k-frags = 96 VGPR.
    short8 whh[3][4];
#pragma unroll
    for (int i = 0; i < 3; i++)
#pragma unroll
        for (int kf = 0; kf < 4; kf++)
            whh[i][kf] = *(const short8*)&wHh[(((wv + 8 * i) * 4 + kf) * 64 + ln) * 8];

    float bihv[3], bhhv[3];
#pragma unroll
    for (int i = 0; i < 3; i++) {
        bihv[i] = bih[(wv + 8 * i) * 16 + l15];
        bhhv[i] = bhh[(wv + 8 * i) * 16 + l15];
    }
    const float fcbv = fcb[wv * 16 + l15];

    for (int idx = tid; idx < 16 * 128; idx += 512) hA[idx] = 0;
    __syncthreads();
    {   // h0 (no reset before step 0)
        const int b = tid >> 7, col = tid & 127;
        float h = h0[(size_t)(bg0 + b) * Hd + col];
        hF[b * 128 + col] = h;
        hA[b * 128 + (((col >> 3) ^ b) * 8) + (col & 7)] = f2bf(h);
    }
    __syncthreads();

    for (int ch = 0; ch < NCH; ch++) {
        const int t0 = ch * CHUNK;
        if (tid < 64)
            doneL[tid] = done[(size_t)(bg0 + (tid & 3)) * Tt + t0 + (tid >> 2)];

        // ---- Phase A: xi = x @ W_ih^T + b_ih for this chunk ----
        // rows 0..63 = tloc*4 + b
#pragma unroll 1
        for (int mt = 0; mt < 4; mt++) {
            const int row = mt * 16 + l15;
            const float* xp =
                x + ((size_t)(bg0 + (row & 3)) * Tt + (t0 + (row >> 2))) * Dd;
            short8 af[4];
#pragma unroll
            for (int kf = 0; kf < 4; kf++) {
                const int k0 = kf * 32 + 8 * lg;
                f32x4 u = *(const f32x4*)&xp[k0];
                f32x4 v = *(const f32x4*)&xp[k0 + 4];
                short8 a;
                a[0] = f2bf(u[0]); a[1] = f2bf(u[1]); a[2] = f2bf(u[2]); a[3] = f2bf(u[3]);
                a[4] = f2bf(v[0]); a[5] = f2bf(v[1]); a[6] = f2bf(v[2]); a[7] = f2bf(v[3]);
                af[kf] = a;
            }
            f32x4 c0 = {0.f,0.f,0.f,0.f}, c1 = {0.f,0.f,0.f,0.f}, c2 = {0.f,0.f,0.f,0.f};
#pragma unroll
            for (int kf = 0; kf < 4; kf++) {   // stream W_ih frags from L1/L2
                short8 w0 = *(const short8*)&wIh[(((wv     ) * 4 + kf) * 64 + ln) * 8];
                short8 w1 = *(const short8*)&wIh[(((wv +  8) * 4 + kf) * 64 + ln) * 8];
                short8 w2 = *(const short8*)&wIh[(((wv + 16) * 4 + kf) * 64 + ln) * 8];
                c0 = __builtin_amdgcn_mfma_f32_16x16x32_bf16(af[kf], w0, c0, 0, 0, 0);
                c1 = __builtin_amdgcn_mfma_f32_16x16x32_bf16(af[kf], w1, c1, 0, 0, 0);
                c2 = __builtin_amdgcn_mfma_f32_16x16x32_bf16(af[kf], w2, c2, 0, 0, 0);
            }
#pragma unroll
            for (int i = 0; i < 3; i++) {
                const int col = (wv + 8 * i) * 16 + l15;
                const f32x4 cc = (i == 0) ? c0 : (i == 1) ? c1 : c2;
#pragma unroll
                for (int r = 0; r < 4; r++) {
                    const int rw = mt * 16 + lg * 4 + r;
                    xiL[rw * 384 + (((col >> 3) ^ (rw & 15)) * 8) + (col & 7)] =
                        f2bf(cc[r] + bihv[i]);
                }
            }
        }
        __syncthreads();

        // ---- Phase B: 16 recurrent steps ----
        for (int tl = 0; tl < CHUNK; tl++) {
            f32x4 g0 = {0.f,0.f,0.f,0.f}, g1 = {0.f,0.f,0.f,0.f}, g2 = {0.f,0.f,0.f,0.f};
#pragma unroll
            for (int kf = 0; kf < 4; kf++) {
                const int p = (kf * 4 + lg) ^ l15;
                short8 ha = *(const short8*)&hA[l15 * 128 + p * 8];
                g0 = __builtin_amdgcn_mfma_f32_16x16x32_bf16(ha, whh[0][kf], g0, 0, 0, 0);
                g1 = __builtin_amdgcn_mfma_f32_16x16x32_bf16(ha, whh[1][kf], g1, 0, 0, 0);
                g2 = __builtin_amdgcn_mfma_f32_16x16x32_bf16(ha, whh[2][kf], g2, 0, 0, 0);
            }
            if (ln < 16) {   // rows 0..3 (= batches) are the valid C rows
#pragma unroll
                for (int r = 0; r < 4; r++) {
                    ghL[r * 384 + wv * 16 + ln]        = g0[r] + bhhv[0];
                    ghL[r * 384 + (wv + 8) * 16 + ln]  = g1[r] + bhhv[1];
                    ghL[r * 384 + (wv + 16) * 16 + ln] = g2[r] + bhhv[2];
                }
            }
            __syncthreads();
            {   // gates: one thread per (batch, hidden-col)
                const int b = tid >> 7, col = tid & 127;
                const int row = tl * 4 + b;
                const int rs = row & 15;
                float xr = bf2f(xiL[row * 384 + ((((col      ) >> 3) ^ rs) * 8) + (col & 7)]);
                float xz = bf2f(xiL[row * 384 + ((((col + 128) >> 3) ^ rs) * 8) + (col & 7)]);
                float xn = bf2f(xiL[row * 384 + ((((col + 256) >> 3) ^ rs) * 8) + (col & 7)]);
                float gr = ghL[b * 384 + col];
                float gz = ghL[b * 384 + col + 128];
                float gn = ghL[b * 384 + col + 256];
                float rg = 1.f / (1.f + __expf(-(xr + gr)));
                float zg = 1.f / (1.f + __expf(-(xz + gz)));
                float aa = xn + rg * gn;
                float ng = 1.f - 2.f / (__expf(2.f * aa) + 1.f);   // tanh
                float hp = hF[b * 128 + col];
                float hn = (1.f - zg) * ng + zg * hp;              // un-reset h_t
                fcA[row * 128 + (((col >> 3) ^ rs) * 8) + (col & 7)] = f2bf(hn);
                if (t0 + tl == Tt - 1)
                    hlast[(size_t)(bg0 + b) * Hd + col] = hn;
                float rst = doneL[tl * 4 + b] ? 0.f : 1.f;         // reset for step t+1
                float hx = hn * rst;
                hF[b * 128 + col] = hx;
                hA[b * 128 + (((col >> 3) ^ b) * 8) + (col & 7)] = f2bf(hx);
            }
            __syncthreads();
        }

        // ---- Phase C: out = elu(h_chunk @ fc_W^T + fc_b) ----
#pragma unroll 1
        for (int mt = 0; mt < 4; mt++) {
            f32x4 c = {0.f,0.f,0.f,0.f};
#pragma unroll
            for (int kf = 0; kf < 4; kf++) {
                short8 w = *(const short8*)&wFc[((wv * 4 + kf) * 64 + ln) * 8];
                const int p = (kf * 4 + lg) ^ l15;
                short8 a = *(const short8*)&fcA[(mt * 16 + l15) * 128 + p * 8];
                c = __builtin_amdgcn_mfma_f32_16x16x32_bf16(a, w, c, 0, 0, 0);
            }
            const int col = wv * 16 + l15;
#pragma unroll
            for (int r = 0; r < 4; r++) {
                const int rw = mt * 16 + lg * 4 + r;
                float v = c[r] + fcbv;
                v = v > 0.f ? v : (__expf(v) - 1.f);
                out[((size_t)(bg0 + (rw & 3)) * Tt + (t0 + (rw >> 2))) * Hd + col] = v;
            }
        }
        __syncthreads();
    }
}

extern "C" void kernel_launch(void* const* d_in, const int* in_sizes, int n_in,
                              void* d_out, int out_size, void* d_ws, size_t ws_size,
                              hipStream_t stream) {
    const float* x   = (const float*)d_in[0];
    const float* h0  = (const float*)d_in[1];
    const int*   dn  = (const int*)d_in[2];
    const float* Wih = (const float*)d_in[3];
    const float* Whh = (const float*)d_in[4];
    const float* bih = (const float*)d_in[5];
    const float* bhh = (const float*)d_in[6];
    const float* fcW = (const float*)d_in[7];
    const float* fcb = (const float*)d_in[8];

    short* wIh = (short*)d_ws;            // 24*4*64*8 shorts = 96 KB
    short* wHh = wIh + 6144 * 8;          // 96 KB
    short* wFc = wHh + 6144 * 8;          // 32 KB
    float* out = (float*)d_out;
    float* hlast = out + (size_t)Bb * Tt * Hd;

    prep_weights<<<56, 256, 0, stream>>>(Wih, Whh, fcW, wIh, wHh, wFc);
    gru_fused<<<Bb / BB, 512, 0, stream>>>(x, h0, dn, bih, bhh, fcb,
                                           wIh, wHh, wFc, out, hlast);
}